// Round 1
// 33292.892 us; speedup vs baseline: 2.2092x; 2.2092x over previous
//
#include <hip/hip_runtime.h>
#include <stdint.h>

// LayerNorm-LSTM, T=1024 B=64 D=512 H=512, fp32. Persistent 256 wgs x 512 thr.
// wg g owns gate cols [8g, 8g+8). v2 vs v1 (70.5 ms):
//  - NO agent release/acquire fences (no buffer_wbl2/buffer_inv). The only
//    cross-wg data (graw 512KB, hbuf 128KB) moves through explicit
//    device-scope (sc1) loads/stores that bypass L1/L2. W, x, pg stay
//    L2-resident across all 1024 steps.
//  - Hierarchical monotonic grid barrier (16 groups x 16 wgs), relaxed agent
//    atomics, counters count up forever (no reset race). arrive/wait split:
//    the x-GEMM for t+1 runs inside the barrier-latency shadow (half per
//    barrier).
//  - hbuf repacked [k/4][b][4]: h-GEMM issues 16 independent dwordx4 device
//    loads (one L3 round trip, full MLP).
//  - c state in registers (cws buffer eliminated).

typedef float f32x4 __attribute__((ext_vector_type(4)));

#define NBLK 256
#define NT   512   // 8 waves

__device__ __forceinline__ float sigm(float x){ return 1.f / (1.f + __expf(-x)); }
__device__ __forceinline__ float tanhp(float x){
  float e = __expf(-2.f * fabsf(x));
  float t = (1.f - e) / (1.f + e);
  return x < 0.f ? -t : t;
}

// device-coherent (agent-scope) access: sc1 bypasses L1/L2, hits L3 point of
// coherence. Loads are raw asm (not counter-tracked by compiler) -> every use
// must come after VM_DRAIN (waitcnt + sched_barrier per guide rule #18).
#define LD_DEV_X4(d, p) asm volatile("global_load_dwordx4 %0, %1, off sc1" : "=v"(d) : "v"(p))
#define LD_DEV(d, p)    asm volatile("global_load_dword %0, %1, off sc1"   : "=v"(d) : "v"(p))
#define ST_DEV_X4(p, v) asm volatile("global_store_dwordx4 %0, %1, off sc1" :: "v"(p), "v"(v) : "memory")
#define ST_DEV(p, v)    asm volatile("global_store_dword %0, %1, off sc1"   :: "v"(p), "v"(v) : "memory")
#define VM_DRAIN()      do { asm volatile("s_waitcnt vmcnt(0)" ::: "memory"); \
                             __builtin_amdgcn_sched_barrier(0); } while (0)

// Monotonic hierarchical barrier. bar[grp*32] = group counters (16 groups,
// separate 128B lines), bar[512] = global counter, bar[544] = generation.
// Data visibility: every wave drains its sc1 stores (vmcnt0 => at L3) before
// its wg's arrival RMW issues; each RMW's result is consumed before the next
// level issues, so gen==ph implies all 256 wgs' prior sc1 stores are at L3.
__device__ __forceinline__ void gbar_arrive(int* bar, int grp, int ph){
  VM_DRAIN();
  __syncthreads();
  if (threadIdx.x == 0){
    int old = __hip_atomic_fetch_add(bar + grp * 32, 1, __ATOMIC_RELAXED, __HIP_MEMORY_SCOPE_AGENT);
    if ((old & 15) == 15){
      int o2 = __hip_atomic_fetch_add(bar + 512, 1, __ATOMIC_RELAXED, __HIP_MEMORY_SCOPE_AGENT);
      if ((o2 & 15) == 15)
        __hip_atomic_store(bar + 544, ph, __ATOMIC_RELAXED, __HIP_MEMORY_SCOPE_AGENT);
    }
  }
}

__device__ __forceinline__ void gbar_wait(int* bar, int ph){
  if (threadIdx.x == 0){
    while (__hip_atomic_load(bar + 544, __ATOMIC_RELAXED, __HIP_MEMORY_SCOPE_AGENT) < ph)
      __builtin_amdgcn_s_sleep(1);
  }
  __syncthreads();
}

// hbuf layout: [k>>2][b][k&3]  (f32x4 rows of 64 batch entries)
__global__ void prep_kernel(const float* __restrict__ h0, float* __restrict__ hbuf){
  const int b = blockIdx.x;
  for (int m = threadIdx.x; m < 512; m += blockDim.x)
    hbuf[((m >> 2) * 64 + b) * 4 + (m & 3)] = h0[b * 512 + m];
}

__global__ __launch_bounds__(NT, 1) void lstm_main(
    const float* __restrict__ x,      // [1024][64][512]
    const float* __restrict__ c0,     // [64][512]
    const float* __restrict__ W,      // [1024][2048]
    const float* __restrict__ bias,   // [2048]
    const float* __restrict__ lgg, const float* __restrict__ lgb,  // [2048]
    const float* __restrict__ lcg, const float* __restrict__ lcb,  // [512]
    float* __restrict__ pg,     // [256][64][8]  x-part partial gates (+bias), wg-private
    float* __restrict__ graw,   // [64][2048]    raw gates (device-coherent)
    float* __restrict__ hbuf,   // [128][64][4]  h state (device-coherent)
    int* bar,
    float* __restrict__ out)    // [1024][64][512] ++ h_last[64][512] ++ c_last[64][512]
{
  __shared__ float red[3584];   // 7 waves x 64 lanes x 8
  __shared__ float st[16];      // LN stats: 8 waves x {sum, sumsq}
  const int tid = threadIdx.x, g = blockIdx.x;
  const int wave = __builtin_amdgcn_readfirstlane(tid >> 6);
  const int lane = tid & 63;
  const int k0 = wave * 64;
  const int grp = g >> 4;

  float biasr[8];
  #pragma unroll
  for (int j = 0; j < 8; j++) biasr[j] = bias[g * 8 + j];

  float vgg[4], vgb[4], vcg = 0.f, vcb = 0.f, cv = 0.f;
  if (g < 64){
    #pragma unroll
    for (int r = 0; r < 4; r++){ vgg[r] = lgg[r * 512 + tid]; vgb[r] = lgb[r * 512 + tid]; }
    vcg = lcg[tid]; vcb = lcb[tid];
    cv = c0[g * 512 + tid];
  }

  // x-part GEMM for time tx, half h (i in [8h, 8h+8)), accumulate into a[8].
  auto xgemm_half = [&](int tx, int h, float* a){
    const float* xs = x + (size_t)tx * 32768;                  // [64][512]
    const f32x4* xb = (const f32x4*)(xs + lane * 512 + k0);    // lane = b
    #pragma unroll
    for (int i = h * 8; i < h * 8 + 8; i++){
      f32x4 v = xb[i];
      const float* wr = W + (size_t)(k0 + i * 4) * 2048 + g * 8;  // wave-uniform
      #pragma unroll
      for (int q = 0; q < 4; q++){
        const float* wq = wr + q * 2048;
        float xv = v[q];
        #pragma unroll
        for (int j = 0; j < 8; j++) a[j] = fmaf(xv, wq[j], a[j]);
      }
    }
  };

  auto xgemm_store = [&](float* a){
    if (wave > 0){
      f32x4* dst = (f32x4*)(red + ((wave - 1) * 64 + lane) * 8);
      dst[0] = f32x4{a[0], a[1], a[2], a[3]};
      dst[1] = f32x4{a[4], a[5], a[6], a[7]};
    }
    __syncthreads();
    if (wave == 0){
      #pragma unroll
      for (int w = 0; w < 7; w++){
        const float* p = red + (w * 64 + lane) * 8;
        #pragma unroll
        for (int j = 0; j < 8; j++) a[j] += p[j];
      }
      f32x4* pgw = (f32x4*)(pg + g * 512 + lane * 8);           // wg-private, cached
      pgw[0] = f32x4{a[0] + biasr[0], a[1] + biasr[1], a[2] + biasr[2], a[3] + biasr[3]};
      pgw[1] = f32x4{a[4] + biasr[4], a[5] + biasr[5], a[6] + biasr[6], a[7] + biasr[7]};
    }
  };

  // prologue: x-GEMM for t=0 (pg wg-private; hbuf visible via stream order)
  {
    float xa[8] = {0,0,0,0,0,0,0,0};
    xgemm_half(0, 0, xa);
    xgemm_half(0, 1, xa);
    xgemm_store(xa);
  }

  int ph = 0;
  for (int t = 0; t < 1024; t++){
    // ---- phase 1: h-part GEMM (W rows 512..1023) + pg -> graw ----
    {
      f32x4 hv[16];
      #pragma unroll
      for (int i = 0; i < 16; i++){
        const float* hp = hbuf + ((wave * 16 + i) * 64 + lane) * 4;  // lane = b
        LD_DEV_X4(hv[i], hp);                 // 16 independent L3 loads in flight
      }
      VM_DRAIN();
      float a[8] = {0,0,0,0,0,0,0,0};
      #pragma unroll
      for (int i = 0; i < 16; i++){
        #pragma unroll
        for (int c = 0; c < 4; c++){
          const float* wr = W + (size_t)(512 + k0 + i * 4 + c) * 2048 + g * 8;  // s_load, L2-hot
          float hvv = hv[i][c];
          #pragma unroll
          for (int j = 0; j < 8; j++) a[j] = fmaf(hvv, wr[j], a[j]);
        }
      }
      if (wave > 0){
        f32x4* dst = (f32x4*)(red + ((wave - 1) * 64 + lane) * 8);
        dst[0] = f32x4{a[0], a[1], a[2], a[3]};
        dst[1] = f32x4{a[4], a[5], a[6], a[7]};
      }
      __syncthreads();
      if (wave == 0){
        #pragma unroll
        for (int w = 0; w < 7; w++){
          const float* p = red + (w * 64 + lane) * 8;
          #pragma unroll
          for (int j = 0; j < 8; j++) a[j] += p[j];
        }
        const float* pgr = pg + g * 512 + lane * 8;
        float* gw = graw + lane * 2048 + g * 8;                 // lane = b
        f32x4 v0 = f32x4{a[0] + pgr[0], a[1] + pgr[1], a[2] + pgr[2], a[3] + pgr[3]};
        f32x4 v1 = f32x4{a[4] + pgr[4], a[5] + pgr[5], a[6] + pgr[6], a[7] + pgr[7]};
        ST_DEV_X4(gw, v0);
        ST_DEV_X4(gw + 4, v1);
      }
    }

    // ---- barrier A (graw ready); x-GEMM half 0 hides the latency ----
    ph++;
    gbar_arrive(bar, grp, ph);
    float xa[8] = {0,0,0,0,0,0,0,0};
    if (t < 1023) xgemm_half(t + 1, 0, xa);
    gbar_wait(bar, ph);

    // ---- row work: wg b = batch row b ----
    if (g < 64){
      const int b = g;
      float gv[4];
      const float* gp = graw + b * 2048 + tid;
      LD_DEV(gv[0], gp);
      LD_DEV(gv[1], gp + 512);
      LD_DEV(gv[2], gp + 1024);
      LD_DEV(gv[3], gp + 1536);
      VM_DRAIN();
      float s = 0.f, q = 0.f;
      #pragma unroll
      for (int r = 0; r < 4; r++){ s += gv[r]; q += gv[r] * gv[r]; }
      #pragma unroll
      for (int off = 32; off > 0; off >>= 1){ s += __shfl_xor(s, off, 64); q += __shfl_xor(q, off, 64); }
      if (lane == 0){ st[wave * 2] = s; st[wave * 2 + 1] = q; }
      __syncthreads();
      s = 0.f; q = 0.f;
      #pragma unroll
      for (int w = 0; w < 8; w++){ s += st[w * 2]; q += st[w * 2 + 1]; }
      float mu = s * (1.f / 2048.f);
      float rstd = rsqrtf(fmaxf(q * (1.f / 2048.f) - mu * mu, 0.f) + 1e-5f);
      float n[4];
      #pragma unroll
      for (int r = 0; r < 4; r++) n[r] = (gv[r] - mu) * rstd * vgg[r] + vgb[r];
      float fv = sigm(n[0]), iv = sigm(n[1]), gg = tanhp(n[2]), ov = sigm(n[3]);
      float cr = fv * cv + iv * gg;
      float s2 = cr, q2 = cr * cr;
      #pragma unroll
      for (int off = 32; off > 0; off >>= 1){ s2 += __shfl_xor(s2, off, 64); q2 += __shfl_xor(q2, off, 64); }
      __syncthreads();                              // st reuse
      if (lane == 0){ st[wave * 2] = s2; st[wave * 2 + 1] = q2; }
      __syncthreads();
      s2 = 0.f; q2 = 0.f;
      #pragma unroll
      for (int w = 0; w < 8; w++){ s2 += st[w * 2]; q2 += st[w * 2 + 1]; }
      float mu2 = s2 * (1.f / 512.f);
      float rs2 = rsqrtf(fmaxf(q2 * (1.f / 512.f) - mu2 * mu2, 0.f) + 1e-5f);
      float cn = (cr - mu2) * rs2 * vcg + vcb;
      cv = cn;                                      // c state stays in register
      float hv = ov * tanhp(cn);
      out[(size_t)(t * 64 + b) * 512 + tid] = hv;
      float* hp = hbuf + ((tid >> 2) * 64 + b) * 4 + (tid & 3);
      ST_DEV(hp, hv);
      if (t == 1023){
        out[(size_t)33554432 + b * 512 + tid] = hv;            // h_last
        out[(size_t)33554432 + 32768 + b * 512 + tid] = cn;    // c_last
      }
    }

    // ---- barrier B (hbuf ready); x-GEMM half 1 + reduce hide the latency ----
    if (t < 1023){
      ph++;
      gbar_arrive(bar, grp, ph);
      xgemm_half(t + 1, 1, xa);
      xgemm_store(xa);
      gbar_wait(bar, ph);
    }
  }
}

extern "C" void kernel_launch(void* const* d_in, const int* in_sizes, int n_in,
                              void* d_out, int out_size, void* d_ws, size_t ws_size,
                              hipStream_t stream){
  const float* x    = (const float*)d_in[0];
  const float* h0   = (const float*)d_in[1];
  const float* c0   = (const float*)d_in[2];
  const float* W    = (const float*)d_in[3];
  const float* bias = (const float*)d_in[4];
  const float* lgg  = (const float*)d_in[5];
  const float* lgb  = (const float*)d_in[6];
  const float* lcg  = (const float*)d_in[7];
  const float* lcb  = (const float*)d_in[8];
  float* out = (float*)d_out;

  char* ws = (char*)d_ws;
  int*   bar  = (int*)ws;                           // 4 KB (16 group lines + gcnt + gen)
  float* pg   = (float*)(ws + 4096);                // 512 KB
  float* graw = (float*)(ws + 4096 + 524288);       // 512 KB
  float* hbuf = (float*)(ws + 4096 + 1048576);      // 128 KB
  // total ws use ~1.2 MB

  hipMemsetAsync(bar, 0, 4096, stream);
  prep_kernel<<<64, 256, 0, stream>>>(h0, hbuf);
  lstm_main<<<NBLK, NT, 0, stream>>>(x, c0, W, bias, lgg, lgb, lcg, lcb,
                                     pg, graw, hbuf, bar, out);
}

// Round 2
// 21073.941 us; speedup vs baseline: 3.4901x; 1.5798x over previous
//
#include <hip/hip_runtime.h>
#include <stdint.h>

// LayerNorm-LSTM, T=1024 B=64 D=512 H=512, fp32. Persistent 256 wgs x 512 thr.
// wg g owns gate cols [8g, 8g+8). v3 vs v2 (33.3 ms):
//  - Per-XCD relay barrier release: one elected leader wg per physical XCD
//    (s_getreg HW_REG_XCC_ID) polls the global gen line via sc1 (8 pollers
//    instead of 256), then re-publishes to a per-XCD flag with sc0 (L2
//    write-through). Members poll the flag with sc0 loads (L1-bypass, L2-hit)
//    -> zero L3 polling by 248 wgs, ~0.2us propagation.
//  - Per-XCD h staging: at barrier B the leader copies hbuf (128 KB) from L3
//    into hstage[xcd] with sc0 stores (the loads double as its own h-GEMM
//    operands). Members read h from their local L2 (sc0) instead of 256 wgs
//    all hammering the same L3 lines (32 MB/step -> 1 MB/step L3 traffic).
//  - graw transposed to [b][m][4]: row wg reads one dwordx4 per thread.
//  - One fewer __syncthreads in the LN2 reduction (separate stats buffer).
//  - Member flag polls carry a bounded-spin fallback to the sc1 gen poll so
//    a wrong sc0 assumption fails visibly instead of hanging.

typedef float f32x4 __attribute__((ext_vector_type(4)));

#define NBLK 256
#define NT   512   // 8 waves

__device__ __forceinline__ float sigm(float x){ return 1.f / (1.f + __expf(-x)); }
__device__ __forceinline__ float tanhp(float x){
  float e = __expf(-2.f * fabsf(x));
  float t = (1.f - e) / (1.f + e);
  return x < 0.f ? -t : t;
}

// device-coherent (L3) access
#define LD_DEV_X4(d, p) asm volatile("global_load_dwordx4 %0, %1, off sc1" : "=v"(d) : "v"(p))
#define ST_DEV_X4(p, v) asm volatile("global_store_dwordx4 %0, %1, off sc1" :: "v"(p), "v"(v) : "memory")
#define ST_DEV(p, v)    asm volatile("global_store_dword %0, %1, off sc1"   :: "v"(p), "v"(v) : "memory")
// XCD-local (L2-coherent) access: sc0 = L1-bypass/coherent, writes through to L2.
// nt on loads: don't retain in L1 (belt-and-suspenders against stale L1 lines).
#define LD_L2_X4(d, p)  asm volatile("global_load_dwordx4 %0, %1, off sc0 nt" : "=v"(d) : "v"(p))
#define LD_L2_I(d, p)   asm volatile("global_load_dword %0, %1, off sc0 nt"   : "=v"(d) : "v"(p))
#define ST_L2_X4(p, v)  asm volatile("global_store_dwordx4 %0, %1, off sc0" :: "v"(p), "v"(v) : "memory")
#define ST_L2_I(p, v)   asm volatile("global_store_dword %0, %1, off sc0"   :: "v"(p), "v"(v) : "memory")
#define VM_DRAIN()      do { asm volatile("s_waitcnt vmcnt(0)" ::: "memory"); \
                             __builtin_amdgcn_sched_barrier(0); } while (0)

// Monotonic hierarchical arrival. bar[grp*32] = 16 leaf counters,
// bar[512] = global counter, bar[544] = generation (stores current phase).
__device__ __forceinline__ void gbar_arrive(int* bar, int grp, int ph){
  VM_DRAIN();
  __syncthreads();
  if (threadIdx.x == 0){
    int old = __hip_atomic_fetch_add(bar + grp * 32, 1, __ATOMIC_RELAXED, __HIP_MEMORY_SCOPE_AGENT);
    if ((old & 15) == 15){
      int o2 = __hip_atomic_fetch_add(bar + 512, 1, __ATOMIC_RELAXED, __HIP_MEMORY_SCOPE_AGENT);
      if ((o2 & 15) == 15)
        __hip_atomic_store(bar + 544, ph, __ATOMIC_RELAXED, __HIP_MEMORY_SCOPE_AGENT);
    }
  }
}

// hbuf layout: [k>>2][b][k&3]  (f32x4 rows of 64 batch entries)
__global__ void prep_kernel(const float* __restrict__ h0, float* __restrict__ hbuf){
  const int b = blockIdx.x;
  for (int m = threadIdx.x; m < 512; m += blockDim.x)
    hbuf[((m >> 2) * 64 + b) * 4 + (m & 3)] = h0[b * 512 + m];
}

__global__ __launch_bounds__(NT, 1) void lstm_main(
    const float* __restrict__ x,      // [1024][64][512]
    const float* __restrict__ c0,     // [64][512]
    const float* __restrict__ W,      // [1024][2048]
    const float* __restrict__ bias,   // [2048]
    const float* __restrict__ lgg, const float* __restrict__ lgb,  // [2048]
    const float* __restrict__ lcg, const float* __restrict__ lcb,  // [512]
    float* __restrict__ pg,     // [256][64][8]   x-part partial gates (+bias), wg-private
    float* __restrict__ graw,   // [64][512][4]   raw gates, transposed (device-coherent)
    float* __restrict__ hbuf,   // [128][64][4]   h state (device-coherent)
    int* bar,                   // arrival tree + gen + election counters
    int* flags,                 // [8][32]        per-XCD release flags (L2-coherent)
    float* __restrict__ hstage, // [8][32768]     per-XCD h staging (L2-coherent)
    float* __restrict__ out)    // [1024][64][512] ++ h_last[64][512] ++ c_last[64][512]
{
  __shared__ float red[3584];   // 7 waves x 64 lanes x 8
  __shared__ float st[32];      // LN stats: 8 waves x {sum,sumsq} x 2 buffers
  __shared__ int sh_ld, sh_xcd;
  const int tid = threadIdx.x, g = blockIdx.x;
  const int wave = __builtin_amdgcn_readfirstlane(tid >> 6);
  const int lane = tid & 63;
  const int k0 = wave * 64;
  const int grp = g >> 4;

  // ---- leader election on the physical XCD ----
  if (tid == 0){
    int xc;
    asm volatile("s_getreg_b32 %0, hwreg(HW_REG_XCC_ID)" : "=s"(xc));
    xc &= 7;
    sh_xcd = xc;
    int e = __hip_atomic_fetch_add(bar + 576 + xc * 32, 1, __ATOMIC_RELAXED, __HIP_MEMORY_SCOPE_AGENT);
    sh_ld = (e == 0);
  }
  __syncthreads();
  const int isLeader = sh_ld;
  int*   flag_my   = flags  + sh_xcd * 32;
  float* hstage_my = hstage + sh_xcd * 32768;

  float biasr[8];
  #pragma unroll
  for (int j = 0; j < 8; j++) biasr[j] = bias[g * 8 + j];

  float vgg[4], vgb[4], vcg = 0.f, vcb = 0.f, cv = 0.f;
  if (g < 64){
    #pragma unroll
    for (int r = 0; r < 4; r++){ vgg[r] = lgg[r * 512 + tid]; vgb[r] = lgb[r * 512 + tid]; }
    vcg = lcg[tid]; vcb = lcb[tid];
    cv = c0[g * 512 + tid];
  }

  // member flag poll with bounded-spin fallback to the sc1 gen line
  auto poll_flag = [&](int phv){
    int f, spins = 0;
    do {
      LD_L2_I(f, flag_my);
      asm volatile("s_waitcnt vmcnt(0)" ::: "memory");
      if (f >= phv) break;
      if (++spins > 20000){
        while (__hip_atomic_load(bar + 544, __ATOMIC_RELAXED, __HIP_MEMORY_SCOPE_AGENT) < phv)
          __builtin_amdgcn_s_sleep(1);
        break;
      }
      __builtin_amdgcn_s_sleep(1);
    } while (1);
  };

  // barrier wait, A-type (no payload staging)
  auto waitA = [&](int phv){
    if (tid == 0){
      if (isLeader){
        while (__hip_atomic_load(bar + 544, __ATOMIC_RELAXED, __HIP_MEMORY_SCOPE_AGENT) < phv)
          __builtin_amdgcn_s_sleep(1);
        ST_L2_I(flag_my, phv);
      } else {
        poll_flag(phv);
      }
    }
    __syncthreads();
    __builtin_amdgcn_sched_barrier(0);
  };

  // barrier wait, B-type: stages hbuf -> hstage (leader) / hstage -> hv (member)
  auto waitB = [&](int phv, f32x4* hv){
    if (isLeader){
      if (tid == 0){
        while (__hip_atomic_load(bar + 544, __ATOMIC_RELAXED, __HIP_MEMORY_SCOPE_AGENT) < phv)
          __builtin_amdgcn_s_sleep(1);
      }
      __syncthreads();
      __builtin_amdgcn_sched_barrier(0);
      #pragma unroll
      for (int i = 0; i < 16; i++){
        const float* hp = hbuf + ((wave * 16 + i) * 64 + lane) * 4;
        LD_DEV_X4(hv[i], hp);
      }
      VM_DRAIN();
      #pragma unroll
      for (int i = 0; i < 16; i++){
        float* sp = hstage_my + ((wave * 16 + i) * 64 + lane) * 4;
        ST_L2_X4(sp, hv[i]);
      }
      VM_DRAIN();
      __syncthreads();
      if (tid == 0) ST_L2_I(flag_my, phv);
    } else {
      if (tid == 0) poll_flag(phv);
      __syncthreads();
      __builtin_amdgcn_sched_barrier(0);
      #pragma unroll
      for (int i = 0; i < 16; i++){
        const float* sp = hstage_my + ((wave * 16 + i) * 64 + lane) * 4;
        LD_L2_X4(hv[i], sp);
      }
      VM_DRAIN();
    }
  };

  // x-part GEMM for time tx, half h (i in [8h, 8h+8)), accumulate into a[8].
  auto xgemm_half = [&](int tx, int h, float* a){
    const float* xs = x + (size_t)tx * 32768;                  // [64][512]
    const f32x4* xb = (const f32x4*)(xs + lane * 512 + k0);    // lane = b
    #pragma unroll
    for (int i = h * 8; i < h * 8 + 8; i++){
      f32x4 v = xb[i];
      const float* wr = W + (size_t)(k0 + i * 4) * 2048 + g * 8;  // wave-uniform
      #pragma unroll
      for (int q = 0; q < 4; q++){
        const float* wq = wr + q * 2048;
        float xv = v[q];
        #pragma unroll
        for (int j = 0; j < 8; j++) a[j] = fmaf(xv, wq[j], a[j]);
      }
    }
  };

  auto xgemm_store = [&](float* a){
    if (wave > 0){
      f32x4* dst = (f32x4*)(red + ((wave - 1) * 64 + lane) * 8);
      dst[0] = f32x4{a[0], a[1], a[2], a[3]};
      dst[1] = f32x4{a[4], a[5], a[6], a[7]};
    }
    __syncthreads();
    if (wave == 0){
      #pragma unroll
      for (int w = 0; w < 7; w++){
        const float* p = red + (w * 64 + lane) * 8;
        #pragma unroll
        for (int j = 0; j < 8; j++) a[j] += p[j];
      }
      f32x4* pgw = (f32x4*)(pg + g * 512 + lane * 8);           // wg-private, cached
      pgw[0] = f32x4{a[0] + biasr[0], a[1] + biasr[1], a[2] + biasr[2], a[3] + biasr[3]};
      pgw[1] = f32x4{a[4] + biasr[4], a[5] + biasr[5], a[6] + biasr[6], a[7] + biasr[7]};
    }
  };

  // prologue: x-GEMM for t=0, then a B-type barrier so leaders stage h0
  {
    float xa[8] = {0,0,0,0,0,0,0,0};
    xgemm_half(0, 0, xa);
    xgemm_half(0, 1, xa);
    xgemm_store(xa);
  }

  f32x4 hv[16];
  int ph = 1;
  gbar_arrive(bar, grp, ph);
  waitB(ph, hv);

  for (int t = 0; t < 1024; t++){
    // ---- phase 1: h-part GEMM (W rows 512..1023), hv already in registers ----
    {
      float a[8] = {0,0,0,0,0,0,0,0};
      #pragma unroll
      for (int i = 0; i < 16; i++){
        #pragma unroll
        for (int c = 0; c < 4; c++){
          const float* wr = W + (size_t)(512 + k0 + i * 4 + c) * 2048 + g * 8;  // wave-uniform, L2-hot
          float hvv = hv[i][c];
          #pragma unroll
          for (int j = 0; j < 8; j++) a[j] = fmaf(hvv, wr[j], a[j]);
        }
      }
      if (wave > 0){
        f32x4* dst = (f32x4*)(red + ((wave - 1) * 64 + lane) * 8);
        dst[0] = f32x4{a[0], a[1], a[2], a[3]};
        dst[1] = f32x4{a[4], a[5], a[6], a[7]};
      }
      __syncthreads();
      if (wave == 0){
        #pragma unroll
        for (int w = 0; w < 7; w++){
          const float* p = red + (w * 64 + lane) * 8;
          #pragma unroll
          for (int j = 0; j < 8; j++) a[j] += p[j];
        }
        const float* pgr = pg + g * 512 + lane * 8;
        // transposed store: graw[b][m][r], m = (g&63)*8+j, r = g>>6
        float* gw = graw + lane * 2048 + ((g & 63) * 8) * 4 + (g >> 6);
        #pragma unroll
        for (int j = 0; j < 8; j++){
          float vv = a[j] + pgr[j];
          ST_DEV(gw + j * 4, vv);
        }
      }
    }

    // ---- barrier A (graw ready); x-GEMM half 0 hides the latency ----
    ph++;
    gbar_arrive(bar, grp, ph);
    float xa[8] = {0,0,0,0,0,0,0,0};
    if (t < 1023) xgemm_half(t + 1, 0, xa);
    waitA(ph);

    // ---- row work: wg b = batch row b ----
    if (g < 64){
      const int b = g;
      f32x4 gq;
      const float* gp = graw + b * 2048 + tid * 4;
      LD_DEV_X4(gq, gp);
      VM_DRAIN();
      float gv[4] = {gq[0], gq[1], gq[2], gq[3]};
      float s = 0.f, q = 0.f;
      #pragma unroll
      for (int r = 0; r < 4; r++){ s += gv[r]; q += gv[r] * gv[r]; }
      #pragma unroll
      for (int off = 32; off > 0; off >>= 1){ s += __shfl_xor(s, off, 64); q += __shfl_xor(q, off, 64); }
      if (lane == 0){ st[wave * 2] = s; st[wave * 2 + 1] = q; }
      __syncthreads();
      s = 0.f; q = 0.f;
      #pragma unroll
      for (int w = 0; w < 8; w++){ s += st[w * 2]; q += st[w * 2 + 1]; }
      float mu = s * (1.f / 2048.f);
      float rstd = rsqrtf(fmaxf(q * (1.f / 2048.f) - mu * mu, 0.f) + 1e-5f);
      float n[4];
      #pragma unroll
      for (int r = 0; r < 4; r++) n[r] = (gv[r] - mu) * rstd * vgg[r] + vgb[r];
      float fv = sigm(n[0]), iv = sigm(n[1]), gg = tanhp(n[2]), ov = sigm(n[3]);
      float cr = fv * cv + iv * gg;
      float s2 = cr, q2 = cr * cr;
      #pragma unroll
      for (int off = 32; off > 0; off >>= 1){ s2 += __shfl_xor(s2, off, 64); q2 += __shfl_xor(q2, off, 64); }
      if (lane == 0){ st[16 + wave * 2] = s2; st[16 + wave * 2 + 1] = q2; }
      __syncthreads();
      s2 = 0.f; q2 = 0.f;
      #pragma unroll
      for (int w = 0; w < 8; w++){ s2 += st[16 + w * 2]; q2 += st[16 + w * 2 + 1]; }
      float mu2 = s2 * (1.f / 512.f);
      float rs2 = rsqrtf(fmaxf(q2 * (1.f / 512.f) - mu2 * mu2, 0.f) + 1e-5f);
      float cn = (cr - mu2) * rs2 * vcg + vcb;
      cv = cn;                                      // c state stays in register
      float hv2 = ov * tanhp(cn);
      out[(size_t)(t * 64 + b) * 512 + tid] = hv2;
      float* hp = hbuf + ((tid >> 2) * 64 + b) * 4 + (tid & 3);
      ST_DEV(hp, hv2);
      if (t == 1023){
        out[(size_t)33554432 + b * 512 + tid] = hv2;           // h_last
        out[(size_t)33554432 + 32768 + b * 512 + tid] = cn;    // c_last
      }
    }

    // ---- barrier B (hbuf ready); x-GEMM half 1 + reduce hide the latency ----
    if (t < 1023){
      ph++;
      gbar_arrive(bar, grp, ph);
      xgemm_half(t + 1, 1, xa);
      xgemm_store(xa);
      waitB(ph, hv);
    }
  }
}

extern "C" void kernel_launch(void* const* d_in, const int* in_sizes, int n_in,
                              void* d_out, int out_size, void* d_ws, size_t ws_size,
                              hipStream_t stream){
  const float* x    = (const float*)d_in[0];
  const float* h0   = (const float*)d_in[1];
  const float* c0   = (const float*)d_in[2];
  const float* W    = (const float*)d_in[3];
  const float* bias = (const float*)d_in[4];
  const float* lgg  = (const float*)d_in[5];
  const float* lgb  = (const float*)d_in[6];
  const float* lcg  = (const float*)d_in[7];
  const float* lcb  = (const float*)d_in[8];
  float* out = (float*)d_out;

  char* ws = (char*)d_ws;
  int*   bar    = (int*)ws;                              // 4 KB: leaves, global, gen, elections
  int*   flags  = (int*)(ws + 4096);                     // 4 KB: per-XCD flags
  float* hstage = (float*)(ws + 8192);                   // 1 MB: 8 x 128 KB
  float* pg     = (float*)(ws + 8192 + 1048576);         // 512 KB
  float* graw   = (float*)(ws + 8192 + 1048576 + 524288);   // 512 KB
  float* hbuf   = (float*)(ws + 8192 + 1048576 + 1048576);  // 128 KB
  // total ws use ~2.2 MB

  hipMemsetAsync(ws, 0, 8192, stream);
  prep_kernel<<<64, 256, 0, stream>>>(h0, hbuf);
  lstm_main<<<NBLK, NT, 0, stream>>>(x, c0, W, bias, lgg, lgb, lcg, lcb,
                                     pg, graw, hbuf, bar, flags, hstage, out);
}